// Round 4
// baseline (4982.943 us; speedup 1.0000x reference)
//
#include <hip/hip_runtime.h>

#define N_VUL 100000
#define N_OTH 20000
#define E_NUM 400000
#define K_DIM 256
#define D_OUT 128
#define EPS 1e-8f

__device__ __forceinline__ unsigned short f2b(float f) {
    unsigned int u = __float_as_uint(f);
    u += 0x7FFFu + ((u >> 16) & 1u);          // round-to-nearest-even
    return (unsigned short)(u >> 16);
}
__device__ __forceinline__ float b2f(unsigned short h) {
    return __uint_as_float(((unsigned int)h) << 16);
}

// ---------------- src/dst disambiguation probe ----------------
// etype-0 slice of src_idx is (x % 20000) -> all < 20000.
__global__ __launch_bounds__(256)
void probe_idx(const int* __restrict__ cand, int* __restrict__ flag)
{
    const int e = blockIdx.x * 256 + threadIdx.x;
    if (e >= E_NUM) return;
    int v = cand[e];
    if (v < 0 || v >= N_OTH) atomicOr(flag, 1);   // cand is NOT src_idx
}

// ---------------- projection -> f32 output (ld stride), used for ht into d_out ----------------
__global__ __launch_bounds__(256)
void proj2f(const float* __restrict__ X, const float* __restrict__ W,
            const float* __restrict__ bias, float* __restrict__ Y,
            int ld, int N)
{
    __shared__ float xs[2][K_DIM];
    const int lr = threadIdx.x >> 7;        // 0..1
    const int c  = threadIdx.x & 127;
    const int r  = blockIdx.x * 2 + lr;
    for (int t = threadIdx.x; t < 2 * K_DIM; t += 256) {
        int rr = blockIdx.x * 2 + (t >> 8);
        if (rr >= N) rr = N - 1;
        xs[t >> 8][t & 255] = X[(size_t)rr * K_DIM + (t & 255)];
    }
    __syncthreads();
    if (r >= N) return;
    float acc = bias[c];
    #pragma unroll 8
    for (int k = 0; k < K_DIM; ++k)
        acc = fmaf(xs[lr][k], W[k * D_OUT + c], acc);
    Y[(size_t)r * ld + c] = acc;
}

// ---------------- projection -> bf16 table (ld 128), used for hr tables ----------------
__global__ __launch_bounds__(256)
void proj2b(const float* __restrict__ X, const float* __restrict__ W,
            unsigned short* __restrict__ Y, int N)
{
    __shared__ float xs[2][K_DIM];
    const int lr = threadIdx.x >> 7;
    const int c  = threadIdx.x & 127;
    const int r  = blockIdx.x * 2 + lr;
    for (int t = threadIdx.x; t < 2 * K_DIM; t += 256) {
        int rr = blockIdx.x * 2 + (t >> 8);
        if (rr >= N) rr = N - 1;
        xs[t >> 8][t & 255] = X[(size_t)rr * K_DIM + (t & 255)];
    }
    __syncthreads();
    if (r >= N) return;
    float acc = 0.0f;
    #pragma unroll 8
    for (int k = 0; k < K_DIM; ++k)
        acc = fmaf(xs[lr][k], W[k * D_OUT + c], acc);
    Y[(size_t)r * D_OUT + c] = f2b(acc);
}

// ---------------- row L2 norm: f32 table (ld 256, first 128 cols) ----------------
__global__ __launch_bounds__(256)
void rownorm_f(const float* __restrict__ T, float* __restrict__ nrm, int N)
{
    const int lr = threadIdx.x >> 6;        // 0..3
    const int l  = threadIdx.x & 63;
    const int r  = blockIdx.x * 4 + lr;
    if (r >= N) return;
    float a = T[(size_t)r * 256 + l];
    float b = T[(size_t)r * 256 + 64 + l];
    float s = a * a + b * b;
    #pragma unroll
    for (int m = 32; m; m >>= 1) s += __shfl_xor(s, m);
    if (l == 0) nrm[r] = sqrtf(s);
}

// ---------------- row L2 norm: bf16 table (ld 128) ----------------
__global__ __launch_bounds__(256)
void rownorm_b(const unsigned short* __restrict__ T, float* __restrict__ nrm, int N)
{
    const int lr = threadIdx.x >> 6;
    const int l  = threadIdx.x & 63;
    const int r  = blockIdx.x * 4 + lr;
    if (r >= N) return;
    float a = b2f(T[(size_t)r * D_OUT + l]);
    float b = b2f(T[(size_t)r * D_OUT + 64 + l]);
    float s = a * a + b * b;
    #pragma unroll
    for (int m = 32; m; m >>= 1) s += __shfl_xor(s, m);
    if (l == 0) nrm[r] = sqrtf(s);
}

// ---------------- edge score pass: A bf16 (ld 128), B f32 (ld 256, d_out) ----------------
__global__ __launch_bounds__(256)
void edge_score(const int* __restrict__ pA, const int* __restrict__ pB,
                const int* __restrict__ flag, int et, int Na, int Nb,
                const unsigned short* __restrict__ A,
                const float* __restrict__ B,
                const float* __restrict__ nA, const float* __restrict__ nB,
                float* __restrict__ sc_out, float* __restrict__ ssum,
                float* __restrict__ cnt)
{
    const int e = blockIdx.x * 4 + (threadIdx.x >> 6);
    const int l = threadIdx.x & 63;
    const int* srcp = (*flag) ? pB : pA;
    const int* dstp = (*flag) ? pA : pB;
    int s = srcp[(size_t)et * E_NUM + e];
    int d = dstp[(size_t)et * E_NUM + e];
    s = s < 0 ? 0 : (s >= Na ? Na - 1 : s);
    d = d < 0 ? 0 : (d >= Nb ? Nb - 1 : d);
    const unsigned short* pa = A + (size_t)s * D_OUT;
    const float* pb = B + (size_t)d * 256;
    float dp = b2f(pa[l]) * pb[l] + b2f(pa[64 + l]) * pb[64 + l];
    #pragma unroll
    for (int m = 32; m; m >>= 1) dp += __shfl_xor(dp, m);
    if (l == 0) {
        float v = dp / (fmaxf(nA[s], EPS) * fmaxf(nB[d], EPS));
        sc_out[e] = v;
        atomicAdd(ssum + d, v);
        atomicAdd(cnt + d, 1.0f);
    }
}

// ---------------- per-dst softmax weights for vul ----------------
__global__ __launch_bounds__(256)
void weights_vul(const float* __restrict__ ssum, const float* __restrict__ cnt,
                 float* __restrict__ w)
{
    const int d = blockIdx.x * 256 + threadIdx.x;
    if (d >= N_VUL) return;
    float m0 = ssum[d]             / fmaxf(cnt[d], 1.0f);
    float m1 = ssum[N_VUL + d]     / fmaxf(cnt[N_VUL + d], 1.0f);
    float m2 = ssum[2 * N_VUL + d] / fmaxf(cnt[2 * N_VUL + d], 1.0f);
    float m3 = ssum[3 * N_VUL + d] / fmaxf(cnt[3 * N_VUL + d], 1.0f);
    float e0 = expf(m0), e1 = expf(m1), e2 = expf(m2), e3 = expf(m3);
    float wp = 0.6f / (e0 + e1), wn = 0.4f / (e2 + e3);
    w[d]             = e0 * wp;
    w[N_VUL + d]     = e1 * wp;
    w[2 * N_VUL + d] = e2 * wn;
    w[3 * N_VUL + d] = e3 * wn;
}

// ---------------- edge message pass: agg[d] += w(d) * s_e * M[src] ----------------
__global__ __launch_bounds__(256)
void edge_msg(const int* __restrict__ pA, const int* __restrict__ pB,
              const int* __restrict__ flag, int et, int Na, int Nb,
              const unsigned short* __restrict__ M,
              const float* __restrict__ sc, const float* __restrict__ w,
              float* __restrict__ agg)
{
    const int e = blockIdx.x * 4 + (threadIdx.x >> 6);
    const int l = threadIdx.x & 63;
    const int* srcp = (*flag) ? pB : pA;
    const int* dstp = (*flag) ? pA : pB;
    int s = srcp[(size_t)et * E_NUM + e];
    int d = dstp[(size_t)et * E_NUM + e];
    s = s < 0 ? 0 : (s >= Na ? Na - 1 : s);
    d = d < 0 ? 0 : (d >= Nb ? Nb - 1 : d);
    float f = sc[e];
    if (w) f *= w[d];
    const unsigned short* pm = M + (size_t)s * D_OUT;
    float* pa = agg + (size_t)d * D_OUT;
    atomicAdd(pa + l,      f * b2f(pm[l]));
    atomicAdd(pa + 64 + l, f * b2f(pm[64 + l]));
}

// ---------------- write-out (f32) ----------------
__global__ __launch_bounds__(256)
void emit_half(const float* __restrict__ agg, float* __restrict__ out, int total)
{
    const int i = blockIdx.x * 256 + threadIdx.x;   // over rows*128
    if (i >= total) return;
    const int r = i >> 7, c = i & 127;
    out[(size_t)r * 256 + 128 + c] = agg[i];
}

extern "C" void kernel_launch(void* const* d_in, const int* in_sizes, int n_in,
                              void* d_out, int out_size, void* d_ws, size_t ws_size,
                              hipStream_t stream)
{
    // ---- size-based input resolution ----
    int i_fv = 0, i_fo = 1, i_We = 2, i_Wn = 3, i_bn = 4, i_iA = 5, i_iB = 6;
    {
        int a = -1, b = -1;
        for (int i = 0; i < n_in; ++i) {
            switch (in_sizes[i]) {
                case 25600000: i_fv = i; break;                 // feat_vul
                case 20480000: i_fo = i; break;                 // feat_other
                case   262144: i_We = i; break;                 // We
                case   163840: i_Wn = i; break;                 // Wn
                case      640: i_bn = i; break;                 // bn
                case  3200000: if (a < 0) a = i; else b = i; break;
                default: break;
            }
        }
        if (a >= 0 && b >= 0) { i_iA = a; i_iB = b; }
    }
    const float* feat_vul = (const float*)d_in[i_fv];
    const float* feat_oth = (const float*)d_in[i_fo];   // [4][N_OTH][256]
    const float* We = (const float*)d_in[i_We];         // [8][256][128]
    const float* Wn = (const float*)d_in[i_Wn];         // [5][256][128]
    const float* bn = (const float*)d_in[i_bn];         // [5][128]
    const int* idxA = (const int*)d_in[i_iA];
    const int* idxB = (const int*)d_in[i_iB];
    float* out = (float*)d_out;                         // reference output dtype = float32

    // ---- workspace carve ----
    float* ssumV  = (float*)d_ws;                         // 4*N_VUL
    float* cntV   = ssumV + (size_t)4 * N_VUL;            // 4*N_VUL
    float* ssumO  = cntV  + (size_t)4 * N_VUL;            // 4*N_OTH
    float* cntO   = ssumO + (size_t)4 * N_OTH;            // 4*N_OTH
    float* aggV   = cntO  + (size_t)4 * N_OTH;            // N_VUL*128
    float* aggO   = aggV  + (size_t)N_VUL * 128;          // 4*N_OTH*128
    int*   flag   = (int*)(aggO + (size_t)4 * N_OTH * 128); // 4 ints
    float* scores = (float*)(flag + 4);                   // 8*E
    float* wV     = scores + (size_t)8 * E_NUM;           // 4*N_VUL
    float* nrmHt  = wV    + (size_t)4 * N_VUL;            // N_VUL + 4*N_OTH
    float* nrmHrS = nrmHt + (size_t)(N_VUL + 4 * N_OTH);  // 4*N_OTH
    float* nrmHrB = nrmHrS + (size_t)4 * N_OTH;           // N_VUL
    unsigned short* hrS = (unsigned short*)(nrmHrB + N_VUL);  // 4*N_OTH*128 bf16
    unsigned short* hrB = hrS + (size_t)4 * N_OTH * 128;      // N_VUL*128 bf16 (reused)

    const size_t zero_bytes = ((size_t)8 * N_VUL + (size_t)8 * N_OTH +
                               (size_t)N_VUL * 128 + (size_t)4 * N_OTH * 128) * 4 + 16;
    hipMemsetAsync(d_ws, 0, zero_bytes, stream);

    probe_idx<<<(E_NUM + 255) / 256, 256, 0, stream>>>(idxA, flag);

    const size_t OUT0 = (size_t)N_VUL * 256;

    // ht[n] -> d_out first half (f32, ld 256), then norms
    proj2f<<<N_VUL / 2, 256, 0, stream>>>(feat_vul, Wn, bn, out, 256, N_VUL);
    for (int n = 1; n <= 4; ++n)
        proj2f<<<N_OTH / 2, 256, 0, stream>>>(
            feat_oth + (size_t)(n - 1) * N_OTH * K_DIM,
            Wn + (size_t)n * K_DIM * D_OUT, bn + (size_t)n * D_OUT,
            out + OUT0 + (size_t)(n - 1) * N_OTH * 256, 256, N_OTH);
    rownorm_f<<<(N_VUL + 3) / 4, 256, 0, stream>>>(out, nrmHt, N_VUL);
    for (int n = 1; n <= 4; ++n)
        rownorm_f<<<N_OTH / 4, 256, 0, stream>>>(
            out + OUT0 + (size_t)(n - 1) * N_OTH * 256,
            nrmHt + N_VUL + (size_t)(n - 1) * N_OTH, N_OTH);

    // etypes 0..3 (src = other types)
    for (int i = 0; i < 4; ++i) {
        unsigned short* T = hrS + (size_t)i * N_OTH * D_OUT;
        proj2b<<<N_OTH / 2, 256, 0, stream>>>(
            feat_oth + (size_t)i * N_OTH * K_DIM,
            We + (size_t)i * K_DIM * D_OUT, T, N_OTH);
        rownorm_b<<<N_OTH / 4, 256, 0, stream>>>(T, nrmHrS + (size_t)i * N_OTH, N_OTH);
        edge_score<<<E_NUM / 4, 256, 0, stream>>>(
            idxA, idxB, flag, i, N_OTH, N_VUL,
            T, out, nrmHrS + (size_t)i * N_OTH, nrmHt,
            scores + (size_t)i * E_NUM, ssumV + (size_t)i * N_VUL, cntV + (size_t)i * N_VUL);
    }
    // etypes 4..7 (src = vul): reuse ONE hrB buffer; after j=3 it holds We[7] proj
    // == hr_final[0] (reference overwrite semantics) for messages.
    for (int j = 0; j < 4; ++j) {
        proj2b<<<N_VUL / 2, 256, 0, stream>>>(
            feat_vul, We + (size_t)(4 + j) * K_DIM * D_OUT, hrB, N_VUL);
        rownorm_b<<<(N_VUL + 3) / 4, 256, 0, stream>>>(hrB, nrmHrB, N_VUL);
        edge_score<<<E_NUM / 4, 256, 0, stream>>>(
            idxA, idxB, flag, 4 + j, N_VUL, N_OTH,
            hrB, out + OUT0 + (size_t)j * N_OTH * 256,
            nrmHrB, nrmHt + N_VUL + (size_t)j * N_OTH,
            scores + (size_t)(4 + j) * E_NUM, ssumO + (size_t)j * N_OTH, cntO + (size_t)j * N_OTH);
    }

    weights_vul<<<(N_VUL + 255) / 256, 256, 0, stream>>>(ssumV, cntV, wV);

    // message passes
    for (int i = 0; i < 4; ++i)
        edge_msg<<<E_NUM / 4, 256, 0, stream>>>(
            idxA, idxB, flag, i, N_OTH, N_VUL,
            hrS + (size_t)i * N_OTH * D_OUT,
            scores + (size_t)i * E_NUM, wV + (size_t)i * N_VUL, aggV);
    for (int j = 0; j < 4; ++j)
        edge_msg<<<E_NUM / 4, 256, 0, stream>>>(
            idxA, idxB, flag, 4 + j, N_VUL, N_OTH,
            hrB, scores + (size_t)(4 + j) * E_NUM, nullptr,
            aggO + (size_t)j * N_OTH * D_OUT);

    emit_half<<<(N_VUL * 128 + 255) / 256, 256, 0, stream>>>(aggV, out, N_VUL * 128);
    emit_half<<<(4 * N_OTH * 128 + 255) / 256, 256, 0, stream>>>(aggO, out + OUT0, 4 * N_OTH * 128);
}

// Round 5
// 2440.253 us; speedup vs baseline: 2.0420x; 2.0420x over previous
//
#include <hip/hip_runtime.h>

#define N_VUL 100000
#define N_OTH 20000
#define E_NUM 400000
#define K_DIM 256
#define D_OUT 128
#define EPS 1e-8f
#define LDW 264   // padded LDS row (bf16 elems): 2-way bank conflicts only

typedef __attribute__((ext_vector_type(8))) short bf16x8;
typedef __attribute__((ext_vector_type(4))) float f32x4;

__device__ __forceinline__ unsigned short f2b(float f) {
    unsigned int u = __float_as_uint(f);
    u += 0x7FFFu + ((u >> 16) & 1u);          // round-to-nearest-even
    return (unsigned short)(u >> 16);
}
__device__ __forceinline__ float b2f(unsigned short h) {
    return __uint_as_float(((unsigned int)h) << 16);
}

// ---------------- src/dst disambiguation probe (proven r4) ----------------
__global__ __launch_bounds__(256)
void probe_idx(const int* __restrict__ cand, int* __restrict__ flag)
{
    const int e = blockIdx.x * 256 + threadIdx.x;
    if (e >= E_NUM) return;
    int v = cand[e];
    if (v < 0 || v >= N_OTH) atomicOr(flag, 1);
}

// ---------------- weight pack: We[8]/Wn[5] f32 [k][n] -> Wb[13][n][k] bf16 ----------------
// order: 0=Wn0, 1..4=We4..7, 5=Wn1,6=We0, 7=Wn2,8=We1, 9=Wn3,10=We2, 11=Wn4,12=We3
__global__ __launch_bounds__(256)
void pack_w(const float* __restrict__ We, const float* __restrict__ Wn,
            unsigned short* __restrict__ Wb)
{
    const int id = blockIdx.x * 256 + threadIdx.x;
    if (id >= 13 * 32768) return;
    const int wp = id >> 15;
    const int n  = (id >> 8) & 127;
    const int k  = id & 255;
    const float* S;
    if (wp == 0)      S = Wn;
    else if (wp <= 4) S = We + (size_t)(3 + wp) * 32768;
    else if (wp & 1)  S = Wn + (size_t)((wp - 3) >> 1) * 32768;
    else              S = We + (size_t)((wp - 6) >> 1) * 32768;
    Wb[id] = f2b(S[k * D_OUT + n]);
}

// ---------------- fused MFMA projection: Y_w = X @ W_w (+bias for w=0) ----------------
// X[N,256] f32; Wb[NW][128][256] bf16 (n-major,k-contig); tabs = NW contiguous
// bf16 tables of N*128; w=0 additionally -> outF (f32, ld 256) with bias.
__global__ __launch_bounds__(256)
void proj_mfma(const float* __restrict__ X, const unsigned short* __restrict__ Wb,
               const float* __restrict__ bias, float* __restrict__ outF,
               unsigned short* __restrict__ tabs, int NW, int N)
{
    __shared__ unsigned short xs[64 * LDW];
    const int tid  = threadIdx.x;
    const int wave = tid >> 6, lane = tid & 63;
    const int r0   = blockIdx.x * 64;

    // stage 64x256 X tile -> bf16 LDS
    #pragma unroll
    for (int c = 0; c < 16; ++c) {
        int f = c * 256 + tid;              // float4 index in tile
        int row = f >> 6, col4 = f & 63;
        int gr = r0 + row; if (gr >= N) gr = N - 1;
        float4 v = *(const float4*)(X + (size_t)gr * K_DIM + col4 * 4);
        unsigned short* p = xs + row * LDW + col4 * 4;
        p[0] = f2b(v.x); p[1] = f2b(v.y); p[2] = f2b(v.z); p[3] = f2b(v.w);
    }
    __syncthreads();

    const int n0   = wave * 32;
    const int arow = lane & 15, akd = (lane >> 4) * 8;
    const int bcol = lane & 15, bkd = (lane >> 4) * 8;
    const int rsub = (lane >> 4) * 4;

    float bias0 = 0.f, bias1 = 0.f;
    if (bias) { bias0 = bias[n0 + bcol]; bias1 = bias[n0 + 16 + bcol]; }

    for (int w = 0; w < NW; ++w) {
        f32x4 acc[4][2];
        #pragma unroll
        for (int m = 0; m < 4; ++m) {
            acc[m][0] = (f32x4){0.f, 0.f, 0.f, 0.f};
            acc[m][1] = (f32x4){0.f, 0.f, 0.f, 0.f};
        }
        const unsigned short* wb = Wb + (size_t)w * 128 * 256;
        #pragma unroll
        for (int k = 0; k < 8; ++k) {
            bf16x8 b0 = *(const bf16x8*)(wb + (size_t)(n0 + bcol) * 256 + k * 32 + bkd);
            bf16x8 b1 = *(const bf16x8*)(wb + (size_t)(n0 + 16 + bcol) * 256 + k * 32 + bkd);
            #pragma unroll
            for (int m = 0; m < 4; ++m) {
                bf16x8 a = *(const bf16x8*)(xs + (m * 16 + arow) * LDW + k * 32 + akd);
                acc[m][0] = __builtin_amdgcn_mfma_f32_16x16x32_bf16(a, b0, acc[m][0], 0, 0, 0);
                acc[m][1] = __builtin_amdgcn_mfma_f32_16x16x32_bf16(a, b1, acc[m][1], 0, 0, 0);
            }
        }
        unsigned short* tw = tabs + (size_t)w * N * D_OUT;
        const bool w0 = (w == 0);
        #pragma unroll
        for (int m = 0; m < 4; ++m) {
            #pragma unroll
            for (int nn = 0; nn < 2; ++nn) {
                const int col = n0 + nn * 16 + bcol;
                const float bb = w0 ? (nn ? bias1 : bias0) : 0.f;
                #pragma unroll
                for (int j = 0; j < 4; ++j) {
                    const int row = r0 + m * 16 + rsub + j;
                    if (row < N) {
                        float v = acc[m][nn][j] + bb;
                        tw[(size_t)row * D_OUT + col] = f2b(v);
                        if (w0) outF[(size_t)row * 256 + col] = v;
                    }
                }
            }
        }
    }
}

// ---------------- row L2 norm of bf16 table (ld 128) ----------------
__global__ __launch_bounds__(256)
void rownorm_b(const unsigned short* __restrict__ T, float* __restrict__ nrm, int N)
{
    const int lr = threadIdx.x >> 6;
    const int l  = threadIdx.x & 63;
    const int r  = blockIdx.x * 4 + lr;
    if (r >= N) return;
    float a = b2f(T[(size_t)r * D_OUT + l]);
    float b = b2f(T[(size_t)r * D_OUT + 64 + l]);
    float s = a * a + b * b;
    #pragma unroll
    for (int m = 32; m; m >>= 1) s += __shfl_xor(s, m);
    if (l == 0) nrm[r] = sqrtf(s);
}

// ---------------- edge score pass (etypes 0..3): bf16 A,B; cache score ----------------
__global__ __launch_bounds__(256)
void edge_score(const int* __restrict__ pA, const int* __restrict__ pB,
                const int* __restrict__ flag, int et, int Na, int Nb,
                const unsigned short* __restrict__ A,
                const unsigned short* __restrict__ B,
                const float* __restrict__ nA, const float* __restrict__ nB,
                float* __restrict__ sc_out, float* __restrict__ ssum,
                float* __restrict__ cnt)
{
    const int e = blockIdx.x * 4 + (threadIdx.x >> 6);
    const int l = threadIdx.x & 63;
    const int* srcp = (*flag) ? pB : pA;
    const int* dstp = (*flag) ? pA : pB;
    int s = srcp[(size_t)et * E_NUM + e];
    int d = dstp[(size_t)et * E_NUM + e];
    s = s < 0 ? 0 : (s >= Na ? Na - 1 : s);
    d = d < 0 ? 0 : (d >= Nb ? Nb - 1 : d);
    const unsigned short* pa = A + (size_t)s * D_OUT;
    const unsigned short* pb = B + (size_t)d * D_OUT;
    float dp = b2f(pa[l]) * b2f(pb[l]) + b2f(pa[64 + l]) * b2f(pb[64 + l]);
    #pragma unroll
    for (int m = 32; m; m >>= 1) dp += __shfl_xor(dp, m);
    if (l == 0) {
        float v = dp / (fmaxf(nA[s], EPS) * fmaxf(nB[d], EPS));
        sc_out[e] = v;
        atomicAdd(ssum + d, v);
        atomicAdd(cnt + d, 1.0f);
    }
}

// ---------------- per-dst softmax weights for vul ----------------
__global__ __launch_bounds__(256)
void weights_vul(const float* __restrict__ ssum, const float* __restrict__ cnt,
                 float* __restrict__ w)
{
    const int d = blockIdx.x * 256 + threadIdx.x;
    if (d >= N_VUL) return;
    float m0 = ssum[d]             / fmaxf(cnt[d], 1.0f);
    float m1 = ssum[N_VUL + d]     / fmaxf(cnt[N_VUL + d], 1.0f);
    float m2 = ssum[2 * N_VUL + d] / fmaxf(cnt[2 * N_VUL + d], 1.0f);
    float m3 = ssum[3 * N_VUL + d] / fmaxf(cnt[3 * N_VUL + d], 1.0f);
    float e0 = expf(m0), e1 = expf(m1), e2 = expf(m2), e3 = expf(m3);
    float wp = 0.6f / (e0 + e1), wn = 0.4f / (e2 + e3);
    w[d]             = e0 * wp;
    w[N_VUL + d]     = e1 * wp;
    w[2 * N_VUL + d] = e2 * wn;
    w[3 * N_VUL + d] = e3 * wn;
}

// ---------------- message pass (etypes 0..3): aggV[d] += w(d)*s_e*M[src] ----------------
__global__ __launch_bounds__(256)
void edge_msg(const int* __restrict__ pA, const int* __restrict__ pB,
              const int* __restrict__ flag, int et, int Na, int Nb,
              const unsigned short* __restrict__ M,
              const float* __restrict__ sc, const float* __restrict__ w,
              float* __restrict__ agg)
{
    const int e = blockIdx.x * 4 + (threadIdx.x >> 6);
    const int l = threadIdx.x & 63;
    const int* srcp = (*flag) ? pB : pA;
    const int* dstp = (*flag) ? pA : pB;
    int s = srcp[(size_t)et * E_NUM + e];
    int d = dstp[(size_t)et * E_NUM + e];
    s = s < 0 ? 0 : (s >= Na ? Na - 1 : s);
    d = d < 0 ? 0 : (d >= Nb ? Nb - 1 : d);
    float f = sc[e] * w[d];
    const unsigned short* pm = M + (size_t)s * D_OUT;
    float* pa = agg + (size_t)d * D_OUT;
    atomicAdd(pa + l,      f * b2f(pm[l]));
    atomicAdd(pa + 64 + l, f * b2f(pm[64 + l]));
}

// ---------------- fused score+message (etypes 4..7): weight==1 ----------------
__global__ __launch_bounds__(256)
void edge_sm(const int* __restrict__ pA, const int* __restrict__ pB,
             const int* __restrict__ flag, int et, int Na, int Nb,
             const unsigned short* __restrict__ A,     // score src table (hrB[j])
             const unsigned short* __restrict__ B,     // htb of dst type
             const unsigned short* __restrict__ M,     // message table (hrB[3])
             const float* __restrict__ nA, const float* __restrict__ nB,
             float* __restrict__ agg)
{
    const int e = blockIdx.x * 4 + (threadIdx.x >> 6);
    const int l = threadIdx.x & 63;
    const int* srcp = (*flag) ? pB : pA;
    const int* dstp = (*flag) ? pA : pB;
    int s = srcp[(size_t)et * E_NUM + e];
    int d = dstp[(size_t)et * E_NUM + e];
    s = s < 0 ? 0 : (s >= Na ? Na - 1 : s);
    d = d < 0 ? 0 : (d >= Nb ? Nb - 1 : d);
    const unsigned short* pa = A + (size_t)s * D_OUT;
    const unsigned short* pb = B + (size_t)d * D_OUT;
    float dp = b2f(pa[l]) * b2f(pb[l]) + b2f(pa[64 + l]) * b2f(pb[64 + l]);
    #pragma unroll
    for (int m = 32; m; m >>= 1) dp += __shfl_xor(dp, m);   // all lanes hold sum
    const float v = dp / (fmaxf(nA[s], EPS) * fmaxf(nB[d], EPS));
    const unsigned short* pm = M + (size_t)s * D_OUT;
    float* pg = agg + (size_t)d * D_OUT;
    atomicAdd(pg + l,      v * b2f(pm[l]));
    atomicAdd(pg + 64 + l, v * b2f(pm[64 + l]));
}

// ---------------- write-out (f32) ----------------
__global__ __launch_bounds__(256)
void emit_half(const float* __restrict__ agg, float* __restrict__ out, int total)
{
    const int i = blockIdx.x * 256 + threadIdx.x;
    if (i >= total) return;
    const int r = i >> 7, c = i & 127;
    out[(size_t)r * 256 + 128 + c] = agg[i];
}

extern "C" void kernel_launch(void* const* d_in, const int* in_sizes, int n_in,
                              void* d_out, int out_size, void* d_ws, size_t ws_size,
                              hipStream_t stream)
{
    // ---- size-based input resolution (proven r4) ----
    int i_fv = 0, i_fo = 1, i_We = 2, i_Wn = 3, i_bn = 4, i_iA = 5, i_iB = 6;
    {
        int a = -1, b = -1;
        for (int i = 0; i < n_in; ++i) {
            switch (in_sizes[i]) {
                case 25600000: i_fv = i; break;
                case 20480000: i_fo = i; break;
                case   262144: i_We = i; break;
                case   163840: i_Wn = i; break;
                case      640: i_bn = i; break;
                case  3200000: if (a < 0) a = i; else b = i; break;
                default: break;
            }
        }
        if (a >= 0 && b >= 0) { i_iA = a; i_iB = b; }
    }
    const float* feat_vul = (const float*)d_in[i_fv];
    const float* feat_oth = (const float*)d_in[i_fo];
    const float* We = (const float*)d_in[i_We];
    const float* Wn = (const float*)d_in[i_Wn];
    const float* bn = (const float*)d_in[i_bn];
    const int* idxA = (const int*)d_in[i_iA];
    const int* idxB = (const int*)d_in[i_iB];
    float* out = (float*)d_out;

    const size_t NV128 = (size_t)N_VUL * 128;   // 12,800,000
    const size_t NO128 = (size_t)N_OTH * 128;   //  2,560,000

    // ---- workspace carve (~276 MB) ----
    int*   flag   = (int*)d_ws;                        // 4 (zeroed)
    float* ssumV  = (float*)d_ws + 4;                  // 4*N_VUL (zeroed)
    float* cntV   = ssumV + (size_t)4 * N_VUL;         // 4*N_VUL (zeroed)
    float* aggV   = cntV  + (size_t)4 * N_VUL;         // NV128   (zeroed)
    float* aggO   = aggV  + NV128;                     // 4*NO128 (zeroed)
    float* scores = aggO  + 4 * NO128;                 // 4*E
    float* wV     = scores + (size_t)4 * E_NUM;        // 4*N_VUL
    float* nrmVul = wV + (size_t)4 * N_VUL;            // 5*N_VUL [ht, hrB0..3]
    float* nrmOth = nrmVul + (size_t)5 * N_VUL;        // 8*N_OTH [ht0,hrS0,ht1,hrS1,...]
    unsigned short* vulTab = (unsigned short*)(nrmOth + (size_t)8 * N_OTH); // 5*NV128 bf16
    unsigned short* othTab = vulTab + 5 * NV128;       // 8*NO128 bf16
    unsigned short* Wb     = othTab + 8 * NO128;       // 13*32768 bf16

    const size_t zero_bytes = (4 + (size_t)8 * N_VUL + NV128 + 4 * NO128) * 4;
    hipMemsetAsync(d_ws, 0, zero_bytes, stream);

    probe_idx<<<(E_NUM + 255) / 256, 256, 0, stream>>>(idxA, flag);
    pack_w<<<(13 * 32768 + 255) / 256, 256, 0, stream>>>(We, Wn, Wb);

    const size_t OUT0 = (size_t)N_VUL * 256;

    // fused projections: vul -> [htbV, hrB0..3]; oth i -> [htbO_i, hrS_i]
    proj_mfma<<<(N_VUL + 63) / 64, 256, 0, stream>>>(
        feat_vul, Wb, bn, out, vulTab, 5, N_VUL);
    for (int i = 0; i < 4; ++i)
        proj_mfma<<<(N_OTH + 63) / 64, 256, 0, stream>>>(
            feat_oth + (size_t)i * N_OTH * K_DIM,
            Wb + (size_t)(5 + 2 * i) * 32768,
            bn + (size_t)(i + 1) * D_OUT,
            out + OUT0 + (size_t)i * N_OTH * 256,
            othTab + (size_t)2 * i * NO128, 2, N_OTH);

    // batched row norms over contiguous tables
    rownorm_b<<<(5 * N_VUL + 3) / 4, 256, 0, stream>>>(vulTab, nrmVul, 5 * N_VUL);
    rownorm_b<<<(8 * N_OTH + 3) / 4, 256, 0, stream>>>(othTab, nrmOth, 8 * N_OTH);

    // etypes 0..3: score pass (dst = vul)
    for (int i = 0; i < 4; ++i)
        edge_score<<<E_NUM / 4, 256, 0, stream>>>(
            idxA, idxB, flag, i, N_OTH, N_VUL,
            othTab + (size_t)(2 * i + 1) * NO128, vulTab,
            nrmOth + (size_t)(2 * i + 1) * N_OTH, nrmVul,
            scores + (size_t)i * E_NUM,
            ssumV + (size_t)i * N_VUL, cntV + (size_t)i * N_VUL);

    weights_vul<<<(N_VUL + 255) / 256, 256, 0, stream>>>(ssumV, cntV, wV);

    // etypes 0..3: weighted message pass
    for (int i = 0; i < 4; ++i)
        edge_msg<<<E_NUM / 4, 256, 0, stream>>>(
            idxA, idxB, flag, i, N_OTH, N_VUL,
            othTab + (size_t)(2 * i + 1) * NO128,
            scores + (size_t)i * E_NUM, wV + (size_t)i * N_VUL, aggV);

    // etypes 4..7: fused score+message (dst = other; weight 1); messages use hrB[3]
    for (int j = 0; j < 4; ++j)
        edge_sm<<<E_NUM / 4, 256, 0, stream>>>(
            idxA, idxB, flag, 4 + j, N_VUL, N_OTH,
            vulTab + (size_t)(1 + j) * NV128,
            othTab + (size_t)2 * j * NO128,
            vulTab + (size_t)4 * NV128,
            nrmVul + (size_t)(1 + j) * N_VUL, nrmOth + (size_t)2 * j * N_OTH,
            aggO + (size_t)j * NO128);

    emit_half<<<((int)NV128 + 255) / 256, 256, 0, stream>>>(aggV, out, (int)NV128);
    emit_half<<<((int)(4 * NO128) + 255) / 256, 256, 0, stream>>>(aggO, out + OUT0, (int)(4 * NO128));
}

// Round 6
// 1297.947 us; speedup vs baseline: 3.8391x; 1.8801x over previous
//
#include <hip/hip_runtime.h>

#define N_VUL 100000
#define N_OTH 20000
#define E_NUM 400000
#define K_DIM 256
#define D_OUT 128
#define EPS 1e-8f
#define LDW 264   // padded LDS row (bf16 elems)
#define VKEYS (4 * N_VUL)            // 400000 vul-side (d,et) keys
#define KEYS  (4 * N_VUL + 4 * N_OTH) // 480000 total keys
#define NBSCAN (KEYS / 256)          // 1875 scan blocks (exact)

typedef __attribute__((ext_vector_type(8))) short bf16x8;
typedef __attribute__((ext_vector_type(4))) float f32x4;

static const size_t NV128 = (size_t)N_VUL * 128;
static const size_t NO128 = (size_t)N_OTH * 128;

__device__ __forceinline__ unsigned short f2b(float f) {
    unsigned int u = __float_as_uint(f);
    u += 0x7FFFu + ((u >> 16) & 1u);
    return (unsigned short)(u >> 16);
}
__device__ __forceinline__ float b2f(unsigned short h) {
    return __uint_as_float(((unsigned int)h) << 16);
}

// ---------------- src/dst disambiguation probe (proven) ----------------
__global__ __launch_bounds__(256)
void probe_idx(const int* __restrict__ cand, int* __restrict__ flag)
{
    const int e = blockIdx.x * 256 + threadIdx.x;
    if (e >= E_NUM) return;
    int v = cand[e];
    if (v < 0 || v >= N_OTH) atomicOr(flag, 1);
}

// ---------------- weight pack (proven) ----------------
__global__ __launch_bounds__(256)
void pack_w(const float* __restrict__ We, const float* __restrict__ Wn,
            unsigned short* __restrict__ Wb)
{
    const int id = blockIdx.x * 256 + threadIdx.x;
    if (id >= 13 * 32768) return;
    const int wp = id >> 15;
    const int n  = (id >> 8) & 127;
    const int k  = id & 255;
    const float* S;
    if (wp == 0)      S = Wn;
    else if (wp <= 4) S = We + (size_t)(3 + wp) * 32768;
    else if (wp & 1)  S = Wn + (size_t)((wp - 3) >> 1) * 32768;
    else              S = We + (size_t)((wp - 6) >> 1) * 32768;
    Wb[id] = f2b(S[k * D_OUT + n]);
}

// ---------------- fused MFMA projection (proven r5) ----------------
__global__ __launch_bounds__(256)
void proj_mfma(const float* __restrict__ X, const unsigned short* __restrict__ Wb,
               const float* __restrict__ bias, float* __restrict__ outF,
               unsigned short* __restrict__ tabs, int NW, int N)
{
    __shared__ unsigned short xs[64 * LDW];
    const int tid  = threadIdx.x;
    const int wave = tid >> 6, lane = tid & 63;
    const int r0   = blockIdx.x * 64;

    #pragma unroll
    for (int c = 0; c < 16; ++c) {
        int f = c * 256 + tid;
        int row = f >> 6, col4 = f & 63;
        int gr = r0 + row; if (gr >= N) gr = N - 1;
        float4 v = *(const float4*)(X + (size_t)gr * K_DIM + col4 * 4);
        unsigned short* p = xs + row * LDW + col4 * 4;
        p[0] = f2b(v.x); p[1] = f2b(v.y); p[2] = f2b(v.z); p[3] = f2b(v.w);
    }
    __syncthreads();

    const int n0   = wave * 32;
    const int arow = lane & 15, akd = (lane >> 4) * 8;
    const int bcol = lane & 15, bkd = (lane >> 4) * 8;
    const int rsub = (lane >> 4) * 4;

    float bias0 = 0.f, bias1 = 0.f;
    if (bias) { bias0 = bias[n0 + bcol]; bias1 = bias[n0 + 16 + bcol]; }

    for (int w = 0; w < NW; ++w) {
        f32x4 acc[4][2];
        #pragma unroll
        for (int m = 0; m < 4; ++m) {
            acc[m][0] = (f32x4){0.f, 0.f, 0.f, 0.f};
            acc[m][1] = (f32x4){0.f, 0.f, 0.f, 0.f};
        }
        const unsigned short* wb = Wb + (size_t)w * 128 * 256;
        #pragma unroll
        for (int k = 0; k < 8; ++k) {
            bf16x8 b0 = *(const bf16x8*)(wb + (size_t)(n0 + bcol) * 256 + k * 32 + bkd);
            bf16x8 b1 = *(const bf16x8*)(wb + (size_t)(n0 + 16 + bcol) * 256 + k * 32 + bkd);
            #pragma unroll
            for (int m = 0; m < 4; ++m) {
                bf16x8 a = *(const bf16x8*)(xs + (m * 16 + arow) * LDW + k * 32 + akd);
                acc[m][0] = __builtin_amdgcn_mfma_f32_16x16x32_bf16(a, b0, acc[m][0], 0, 0, 0);
                acc[m][1] = __builtin_amdgcn_mfma_f32_16x16x32_bf16(a, b1, acc[m][1], 0, 0, 0);
            }
        }
        unsigned short* tw = tabs + (size_t)w * N * D_OUT;
        const bool w0 = (w == 0);
        #pragma unroll
        for (int m = 0; m < 4; ++m) {
            #pragma unroll
            for (int nn = 0; nn < 2; ++nn) {
                const int col = n0 + nn * 16 + bcol;
                const float bb = w0 ? (nn ? bias1 : bias0) : 0.f;
                #pragma unroll
                for (int j = 0; j < 4; ++j) {
                    const int row = r0 + m * 16 + rsub + j;
                    if (row < N) {
                        float v = acc[m][nn][j] + bb;
                        tw[(size_t)row * D_OUT + col] = f2b(v);
                        if (w0) outF[(size_t)row * 256 + col] = v;
                    }
                }
            }
        }
    }
}

// ---------------- row L2 norm of bf16 table (proven) ----------------
__global__ __launch_bounds__(256)
void rownorm_b(const unsigned short* __restrict__ T, float* __restrict__ nrm, int N)
{
    const int lr = threadIdx.x >> 6;
    const int l  = threadIdx.x & 63;
    const int r  = blockIdx.x * 4 + lr;
    if (r >= N) return;
    float a = b2f(T[(size_t)r * D_OUT + l]);
    float b = b2f(T[(size_t)r * D_OUT + 64 + l]);
    float s = a * a + b * b;
    #pragma unroll
    for (int m = 32; m; m >>= 1) s += __shfl_xor(s, m);
    if (l == 0) nrm[r] = sqrtf(s);
}

// ---------------- CSR build: histogram over (dst,etype) keys ----------------
__device__ __forceinline__ int edge_key(const int* pA, const int* pB, int flagv,
                                        int id, int* s_out)
{
    const int et = id / E_NUM;
    const int e  = id - et * E_NUM;
    const int* srcp = flagv ? pB : pA;
    const int* dstp = flagv ? pA : pB;
    int s = srcp[(size_t)et * E_NUM + e];
    int d = dstp[(size_t)et * E_NUM + e];
    if (et < 4) {
        s = s < 0 ? 0 : (s >= N_OTH ? N_OTH - 1 : s);
        d = d < 0 ? 0 : (d >= N_VUL ? N_VUL - 1 : d);
        *s_out = s;
        return d * 4 + et;
    } else {
        s = s < 0 ? 0 : (s >= N_VUL ? N_VUL - 1 : s);
        d = d < 0 ? 0 : (d >= N_OTH ? N_OTH - 1 : d);
        *s_out = s;
        return VKEYS + (et - 4) * N_OTH + d;
    }
}

__global__ __launch_bounds__(256)
void hist_edges(const int* __restrict__ pA, const int* __restrict__ pB,
                const int* __restrict__ flag, int* __restrict__ counts)
{
    const int id = blockIdx.x * 256 + threadIdx.x;
    if (id >= 8 * E_NUM) return;
    int s;
    int key = edge_key(pA, pB, *flag, id, &s);
    atomicAdd(counts + key, 1);
}

__global__ __launch_bounds__(256)
void scan_bsum(const int* __restrict__ counts, int* __restrict__ bsum)
{
    __shared__ int sh[256];
    sh[threadIdx.x] = counts[blockIdx.x * 256 + threadIdx.x];
    __syncthreads();
    for (int st = 128; st; st >>= 1) {
        if (threadIdx.x < st) sh[threadIdx.x] += sh[threadIdx.x + st];
        __syncthreads();
    }
    if (threadIdx.x == 0) bsum[blockIdx.x] = sh[0];
}

__global__ void scan_top(int* __restrict__ bsum, int* __restrict__ offs)
{
    if (threadIdx.x == 0 && blockIdx.x == 0) {
        int run = 0;
        for (int b = 0; b < NBSCAN; ++b) { int t = bsum[b]; bsum[b] = run; run += t; }
        offs[KEYS] = run;
    }
}

__global__ __launch_bounds__(256)
void scan_local(const int* __restrict__ counts, const int* __restrict__ bsum,
                int* __restrict__ offs, int* __restrict__ woff)
{
    __shared__ int sh[256];
    const int i = blockIdx.x * 256 + threadIdx.x;
    const int v = counts[i];
    sh[threadIdx.x] = v;
    __syncthreads();
    for (int st = 1; st < 256; st <<= 1) {
        int t = (threadIdx.x >= st) ? sh[threadIdx.x - st] : 0;
        __syncthreads();
        sh[threadIdx.x] += t;
        __syncthreads();
    }
    const int excl = bsum[blockIdx.x] + sh[threadIdx.x] - v;
    offs[i] = excl;
    woff[i] = excl;
}

__global__ __launch_bounds__(256)
void scatter_edges(const int* __restrict__ pA, const int* __restrict__ pB,
                   const int* __restrict__ flag, int* __restrict__ woff,
                   int* __restrict__ srcs)
{
    const int id = blockIdx.x * 256 + threadIdx.x;
    if (id >= 8 * E_NUM) return;
    int s;
    int key = edge_key(pA, pB, *flag, id, &s);
    int pos = atomicAdd(woff + key, 1);
    srcs[pos] = s;
}

// ---------------- vul destination: scores + softmax + combine, no atomics ----------------
// block = 1 dst, wave et = etype et. agg = sum_et w_et * sum_e v_e * hr_et[src_e]
__global__ __launch_bounds__(256)
void vul_gather(const int* __restrict__ srcs, const int* __restrict__ offs,
                const unsigned short* __restrict__ othTab,
                const unsigned short* __restrict__ vulTab,
                const float* __restrict__ nrmOth, const float* __restrict__ nrmVul,
                float* __restrict__ out)
{
    const int d    = blockIdx.x;
    const int et   = threadIdx.x >> 6;
    const int lane = threadIdx.x & 63;
    __shared__ float ssum_s[4];
    __shared__ float acc_w[4][128];

    const float hb0 = b2f(vulTab[(size_t)d * 128 + lane]);
    const float hb1 = b2f(vulTab[(size_t)d * 128 + 64 + lane]);
    const float nb  = fmaxf(nrmVul[d], EPS);
    const unsigned short* T  = othTab + (size_t)(2 * et + 1) * NO128;
    const float* nA = nrmOth + (size_t)(2 * et + 1) * N_OTH;

    const int k0 = offs[d * 4 + et], k1 = offs[d * 4 + et + 1];
    float acc0 = 0.f, acc1 = 0.f, ss = 0.f;
    for (int p = k0; p < k1; ++p) {
        const int s = srcs[p];
        const float a0 = b2f(T[(size_t)s * 128 + lane]);
        const float a1 = b2f(T[(size_t)s * 128 + 64 + lane]);
        float dp = a0 * hb0 + a1 * hb1;
        #pragma unroll
        for (int m = 32; m; m >>= 1) dp += __shfl_xor(dp, m);
        const float v = dp / (fmaxf(nA[s], EPS) * nb);
        ss += v; acc0 += v * a0; acc1 += v * a1;
    }
    if (lane == 0) ssum_s[et] = ss;
    __syncthreads();

    const int b0 = offs[d * 4], b1 = offs[d * 4 + 1], b2 = offs[d * 4 + 2],
              b3 = offs[d * 4 + 3], b4 = offs[d * 4 + 4];
    const float m0 = ssum_s[0] / fmaxf((float)(b1 - b0), 1.f);
    const float m1 = ssum_s[1] / fmaxf((float)(b2 - b1), 1.f);
    const float m2 = ssum_s[2] / fmaxf((float)(b3 - b2), 1.f);
    const float m3 = ssum_s[3] / fmaxf((float)(b4 - b3), 1.f);
    const float e0 = expf(m0), e1 = expf(m1), e2 = expf(m2), e3 = expf(m3);
    const float wp = 0.6f / (e0 + e1), wn = 0.4f / (e2 + e3);
    const float wet = (et == 0) ? e0 * wp : (et == 1) ? e1 * wp
                    : (et == 2) ? e2 * wn : e3 * wn;
    acc_w[et][lane]      = wet * acc0;
    acc_w[et][64 + lane] = wet * acc1;
    __syncthreads();

    if (threadIdx.x < 128) {
        const int c = threadIdx.x;
        out[(size_t)d * 256 + 128 + c] =
            acc_w[0][c] + acc_w[1][c] + acc_w[2][c] + acc_w[3][c];
    }
}

// ---------------- other destinations: fused score+message gather, weight 1 ----------------
// block = 1 dst, wave j = etype 4+j; writes its own output row directly.
__global__ __launch_bounds__(256)
void oth_gather(const int* __restrict__ srcs, const int* __restrict__ offs,
                const unsigned short* __restrict__ vulTab,
                const unsigned short* __restrict__ othTab,
                const float* __restrict__ nrmVul, const float* __restrict__ nrmOth,
                float* __restrict__ out)
{
    const int d    = blockIdx.x;
    const int j    = threadIdx.x >> 6;
    const int lane = threadIdx.x & 63;

    const int key = VKEYS + j * N_OTH + d;
    const int k0 = offs[key], k1 = offs[key + 1];

    const unsigned short* B = othTab + (size_t)(2 * j) * NO128;
    const float hb0 = b2f(B[(size_t)d * 128 + lane]);
    const float hb1 = b2f(B[(size_t)d * 128 + 64 + lane]);
    const float nb  = fmaxf(nrmOth[(size_t)2 * j * N_OTH + d], EPS);

    const unsigned short* A = vulTab + (size_t)(1 + j) * NV128;
    const unsigned short* M = vulTab + (size_t)4 * NV128;   // hr_final[0] = We[7] proj
    const float* nA = nrmVul + (size_t)(1 + j) * N_VUL;

    float acc0 = 0.f, acc1 = 0.f;
    for (int p = k0; p < k1; ++p) {
        const int s = srcs[p];
        const float a0 = b2f(A[(size_t)s * 128 + lane]);
        const float a1 = b2f(A[(size_t)s * 128 + 64 + lane]);
        float dp = a0 * hb0 + a1 * hb1;
        #pragma unroll
        for (int m = 32; m; m >>= 1) dp += __shfl_xor(dp, m);
        const float v = dp / (fmaxf(nA[s], EPS) * nb);
        float m0, m1;
        if (j == 3) { m0 = a0; m1 = a1; }                   // A == M for j=3
        else { m0 = b2f(M[(size_t)s * 128 + lane]); m1 = b2f(M[(size_t)s * 128 + 64 + lane]); }
        acc0 += v * m0; acc1 += v * m1;
    }
    float* o = out + (size_t)N_VUL * 256 + (size_t)j * N_OTH * 256 + (size_t)d * 256 + 128;
    o[lane]      = acc0;
    o[64 + lane] = acc1;
}

extern "C" void kernel_launch(void* const* d_in, const int* in_sizes, int n_in,
                              void* d_out, int out_size, void* d_ws, size_t ws_size,
                              hipStream_t stream)
{
    // ---- size-based input resolution (proven) ----
    int i_fv = 0, i_fo = 1, i_We = 2, i_Wn = 3, i_bn = 4, i_iA = 5, i_iB = 6;
    {
        int a = -1, b = -1;
        for (int i = 0; i < n_in; ++i) {
            switch (in_sizes[i]) {
                case 25600000: i_fv = i; break;
                case 20480000: i_fo = i; break;
                case   262144: i_We = i; break;
                case   163840: i_Wn = i; break;
                case      640: i_bn = i; break;
                case  3200000: if (a < 0) a = i; else b = i; break;
                default: break;
            }
        }
        if (a >= 0 && b >= 0) { i_iA = a; i_iB = b; }
    }
    const float* feat_vul = (const float*)d_in[i_fv];
    const float* feat_oth = (const float*)d_in[i_fo];
    const float* We = (const float*)d_in[i_We];
    const float* Wn = (const float*)d_in[i_Wn];
    const float* bn = (const float*)d_in[i_bn];
    const int* idxA = (const int*)d_in[i_iA];
    const int* idxB = (const int*)d_in[i_iB];
    float* out = (float*)d_out;

    // ---- workspace carve (~195 MB) ----
    int*   flag   = (int*)d_ws;                         // 4 ints (zeroed)
    int*   counts = flag + 4;                           // KEYS (zeroed)
    int*   offs   = counts + KEYS;                      // KEYS+1
    int*   woff   = offs + KEYS + 1;                    // KEYS
    int*   bsum   = woff + KEYS;                        // NBSCAN (pad to 2048)
    int*   srcs   = bsum + 2048;                        // 8*E_NUM
    float* nrmVul = (float*)(srcs + (size_t)8 * E_NUM); // 5*N_VUL
    float* nrmOth = nrmVul + (size_t)5 * N_VUL;         // 8*N_OTH
    unsigned short* vulTab = (unsigned short*)(nrmOth + (size_t)8 * N_OTH); // 5*NV128
    unsigned short* othTab = vulTab + 5 * NV128;        // 8*NO128
    unsigned short* Wb     = othTab + 8 * NO128;        // 13*32768

    hipMemsetAsync(d_ws, 0, (4 + (size_t)KEYS) * sizeof(int), stream);

    probe_idx<<<(E_NUM + 255) / 256, 256, 0, stream>>>(idxA, flag);
    pack_w<<<(13 * 32768 + 255) / 256, 256, 0, stream>>>(We, Wn, Wb);

    const size_t OUT0 = (size_t)N_VUL * 256;

    // projections: vul -> [ht, hrB0..3]; oth i -> [ht_i, hrS_i]
    proj_mfma<<<(N_VUL + 63) / 64, 256, 0, stream>>>(
        feat_vul, Wb, bn, out, vulTab, 5, N_VUL);
    for (int i = 0; i < 4; ++i)
        proj_mfma<<<(N_OTH + 63) / 64, 256, 0, stream>>>(
            feat_oth + (size_t)i * N_OTH * K_DIM,
            Wb + (size_t)(5 + 2 * i) * 32768,
            bn + (size_t)(i + 1) * D_OUT,
            out + OUT0 + (size_t)i * N_OTH * 256,
            othTab + (size_t)2 * i * NO128, 2, N_OTH);

    rownorm_b<<<(5 * N_VUL + 3) / 4, 256, 0, stream>>>(vulTab, nrmVul, 5 * N_VUL);
    rownorm_b<<<(8 * N_OTH + 3) / 4, 256, 0, stream>>>(othTab, nrmOth, 8 * N_OTH);

    // CSR build over all 8 etypes
    hist_edges<<<(8 * E_NUM + 255) / 256, 256, 0, stream>>>(idxA, idxB, flag, counts);
    scan_bsum<<<NBSCAN, 256, 0, stream>>>(counts, bsum);
    scan_top<<<1, 64, 0, stream>>>(bsum, offs);
    scan_local<<<NBSCAN, 256, 0, stream>>>(counts, bsum, offs, woff);
    scatter_edges<<<(8 * E_NUM + 255) / 256, 256, 0, stream>>>(idxA, idxB, flag, woff, srcs);

    // gather-mode aggregation straight into d_out
    vul_gather<<<N_VUL, 256, 0, stream>>>(srcs, offs, othTab, vulTab, nrmOth, nrmVul, out);
    oth_gather<<<N_OTH, 256, 0, stream>>>(srcs, offs, vulTab, othTab, nrmVul, nrmOth, out);
}

// Round 7
// 1016.267 us; speedup vs baseline: 4.9032x; 1.2772x over previous
//
#include <hip/hip_runtime.h>

#define N_VUL 100000
#define N_OTH 20000
#define E_NUM 400000
#define K_DIM 256
#define D_OUT 128
#define EPS 1e-8f
#define LDW 264   // padded LDS row (bf16 elems)
#define VKEYS (4 * N_VUL)             // 400000 vul-side (d,et) keys
#define KEYS  (4 * N_VUL + 4 * N_OTH) // 480000 total keys
#define NBSCAN (KEYS / 256)           // 1875 scan blocks (exact)

typedef __attribute__((ext_vector_type(8))) short bf16x8;
typedef __attribute__((ext_vector_type(4))) float f32x4;

static const size_t NV128 = (size_t)N_VUL * 128;
static const size_t NO128 = (size_t)N_OTH * 128;

__device__ __forceinline__ unsigned short f2b(float f) {
    unsigned int u = __float_as_uint(f);
    u += 0x7FFFu + ((u >> 16) & 1u);
    return (unsigned short)(u >> 16);
}
__device__ __forceinline__ float b2f(unsigned short h) {
    return __uint_as_float(((unsigned int)h) << 16);
}

// ---------------- src/dst disambiguation probe (proven) ----------------
__global__ __launch_bounds__(256)
void probe_idx(const int* __restrict__ cand, int* __restrict__ flag)
{
    const int e = blockIdx.x * 256 + threadIdx.x;
    if (e >= E_NUM) return;
    int v = cand[e];
    if (v < 0 || v >= N_OTH) atomicOr(flag, 1);
}

// ---------------- weight pack (proven) ----------------
// order: 0=Wn0, 1..4=We4..7, 5=Wn1,6=We0, 7=Wn2,8=We1, 9=Wn3,10=We2, 11=Wn4,12=We3
__global__ __launch_bounds__(256)
void pack_w(const float* __restrict__ We, const float* __restrict__ Wn,
            unsigned short* __restrict__ Wb)
{
    const int id = blockIdx.x * 256 + threadIdx.x;
    if (id >= 13 * 32768) return;
    const int wp = id >> 15;
    const int n  = (id >> 8) & 127;
    const int k  = id & 255;
    const float* S;
    if (wp == 0)      S = Wn;
    else if (wp <= 4) S = We + (size_t)(3 + wp) * 32768;
    else if (wp & 1)  S = Wn + (size_t)((wp - 3) >> 1) * 32768;
    else              S = We + (size_t)((wp - 6) >> 1) * 32768;
    Wb[id] = f2b(S[k * D_OUT + n]);
}

// ---------------- fused MFMA projection ----------------
// w==0 -> f32 ht (+bias) into outF (ld 256); w>0 -> bf16 table (w-1)
__global__ __launch_bounds__(256)
void proj_mfma(const float* __restrict__ X, const unsigned short* __restrict__ Wb,
               const float* __restrict__ bias, float* __restrict__ outF,
               unsigned short* __restrict__ tabs, int NW, int N)
{
    __shared__ unsigned short xs[64 * LDW];
    const int tid  = threadIdx.x;
    const int wave = tid >> 6, lane = tid & 63;
    const int r0   = blockIdx.x * 64;

    #pragma unroll
    for (int c = 0; c < 16; ++c) {
        int f = c * 256 + tid;
        int row = f >> 6, col4 = f & 63;
        int gr = r0 + row; if (gr >= N) gr = N - 1;
        float4 v = *(const float4*)(X + (size_t)gr * K_DIM + col4 * 4);
        unsigned short* p = xs + row * LDW + col4 * 4;
        p[0] = f2b(v.x); p[1] = f2b(v.y); p[2] = f2b(v.z); p[3] = f2b(v.w);
    }
    __syncthreads();

    const int n0   = wave * 32;
    const int arow = lane & 15, akd = (lane >> 4) * 8;
    const int bcol = lane & 15, bkd = (lane >> 4) * 8;
    const int rsub = (lane >> 4) * 4;

    float bias0 = 0.f, bias1 = 0.f;
    if (bias) { bias0 = bias[n0 + bcol]; bias1 = bias[n0 + 16 + bcol]; }

    for (int w = 0; w < NW; ++w) {
        f32x4 acc[4][2];
        #pragma unroll
        for (int m = 0; m < 4; ++m) {
            acc[m][0] = (f32x4){0.f, 0.f, 0.f, 0.f};
            acc[m][1] = (f32x4){0.f, 0.f, 0.f, 0.f};
        }
        const unsigned short* wb = Wb + (size_t)w * 128 * 256;
        #pragma unroll
        for (int k = 0; k < 8; ++k) {
            bf16x8 b0 = *(const bf16x8*)(wb + (size_t)(n0 + bcol) * 256 + k * 32 + bkd);
            bf16x8 b1 = *(const bf16x8*)(wb + (size_t)(n0 + 16 + bcol) * 256 + k * 32 + bkd);
            #pragma unroll
            for (int m = 0; m < 4; ++m) {
                bf16x8 a = *(const bf16x8*)(xs + (m * 16 + arow) * LDW + k * 32 + akd);
                acc[m][0] = __builtin_amdgcn_mfma_f32_16x16x32_bf16(a, b0, acc[m][0], 0, 0, 0);
                acc[m][1] = __builtin_amdgcn_mfma_f32_16x16x32_bf16(a, b1, acc[m][1], 0, 0, 0);
            }
        }
        if (w == 0) {
            #pragma unroll
            for (int m = 0; m < 4; ++m)
                #pragma unroll
                for (int nn = 0; nn < 2; ++nn) {
                    const int col = n0 + nn * 16 + bcol;
                    const float bb = nn ? bias1 : bias0;
                    #pragma unroll
                    for (int j = 0; j < 4; ++j) {
                        const int row = r0 + m * 16 + rsub + j;
                        if (row < N) outF[(size_t)row * 256 + col] = acc[m][nn][j] + bb;
                    }
                }
        } else {
            unsigned short* tw = tabs + (size_t)(w - 1) * N * D_OUT;
            #pragma unroll
            for (int m = 0; m < 4; ++m)
                #pragma unroll
                for (int nn = 0; nn < 2; ++nn) {
                    const int col = n0 + nn * 16 + bcol;
                    #pragma unroll
                    for (int j = 0; j < 4; ++j) {
                        const int row = r0 + m * 16 + rsub + j;
                        if (row < N) tw[(size_t)row * D_OUT + col] = f2b(acc[m][nn][j]);
                    }
                }
        }
    }
}

// ---------------- reciprocal row L2 norm: f32 table (ld 256, cols 0..127) ----------------
__global__ __launch_bounds__(256)
void rownorm_f(const float* __restrict__ T, float* __restrict__ rn, int N)
{
    const int lr = threadIdx.x >> 6;
    const int l  = threadIdx.x & 63;
    const int r  = blockIdx.x * 4 + lr;
    if (r >= N) return;
    float a = T[(size_t)r * 256 + l];
    float b = T[(size_t)r * 256 + 64 + l];
    float s = a * a + b * b;
    #pragma unroll
    for (int m = 32; m; m >>= 1) s += __shfl_xor(s, m);
    if (l == 0) rn[r] = 1.f / fmaxf(sqrtf(s), EPS);
}

// ---------------- reciprocal row L2 norm: bf16 table (ld 128) ----------------
__global__ __launch_bounds__(256)
void rownorm_b(const unsigned short* __restrict__ T, float* __restrict__ rn, int N)
{
    const int lr = threadIdx.x >> 6;
    const int l  = threadIdx.x & 63;
    const int r  = blockIdx.x * 4 + lr;
    if (r >= N) return;
    float a = b2f(T[(size_t)r * D_OUT + l]);
    float b = b2f(T[(size_t)r * D_OUT + 64 + l]);
    float s = a * a + b * b;
    #pragma unroll
    for (int m = 32; m; m >>= 1) s += __shfl_xor(s, m);
    if (l == 0) rn[r] = 1.f / fmaxf(sqrtf(s), EPS);
}

// ---------------- CSR build (proven, scan_top parallelized) ----------------
__device__ __forceinline__ int edge_key(const int* pA, const int* pB, int flagv,
                                        int id, int* s_out)
{
    const int et = id / E_NUM;
    const int e  = id - et * E_NUM;
    const int* srcp = flagv ? pB : pA;
    const int* dstp = flagv ? pA : pB;
    int s = srcp[(size_t)et * E_NUM + e];
    int d = dstp[(size_t)et * E_NUM + e];
    if (et < 4) {
        s = s < 0 ? 0 : (s >= N_OTH ? N_OTH - 1 : s);
        d = d < 0 ? 0 : (d >= N_VUL ? N_VUL - 1 : d);
        *s_out = s;
        return d * 4 + et;
    } else {
        s = s < 0 ? 0 : (s >= N_VUL ? N_VUL - 1 : s);
        d = d < 0 ? 0 : (d >= N_OTH ? N_OTH - 1 : d);
        *s_out = s;
        return VKEYS + (et - 4) * N_OTH + d;
    }
}

__global__ __launch_bounds__(256)
void hist_edges(const int* __restrict__ pA, const int* __restrict__ pB,
                const int* __restrict__ flag, int* __restrict__ counts)
{
    const int id = blockIdx.x * 256 + threadIdx.x;
    if (id >= 8 * E_NUM) return;
    int s;
    int key = edge_key(pA, pB, *flag, id, &s);
    atomicAdd(counts + key, 1);
}

__global__ __launch_bounds__(256)
void scan_bsum(const int* __restrict__ counts, int* __restrict__ bsum)
{
    __shared__ int sh[256];
    sh[threadIdx.x] = counts[blockIdx.x * 256 + threadIdx.x];
    __syncthreads();
    for (int st = 128; st; st >>= 1) {
        if (threadIdx.x < st) sh[threadIdx.x] += sh[threadIdx.x + st];
        __syncthreads();
    }
    if (threadIdx.x == 0) bsum[blockIdx.x] = sh[0];
}

// single block, 256 threads: exclusive scan of bsum[NBSCAN]
__global__ __launch_bounds__(256)
void scan_top(int* __restrict__ bsum, int* __restrict__ offs)
{
    __shared__ int sh[256];
    __shared__ int carry_s;
    if (threadIdx.x == 0) carry_s = 0;
    __syncthreads();
    for (int base = 0; base < NBSCAN; base += 256) {
        const int i = base + threadIdx.x;
        const int v = (i < NBSCAN) ? bsum[i] : 0;
        sh[threadIdx.x] = v;
        __syncthreads();
        for (int st = 1; st < 256; st <<= 1) {
            int t = (threadIdx.x >= st) ? sh[threadIdx.x - st] : 0;
            __syncthreads();
            sh[threadIdx.x] += t;
            __syncthreads();
        }
        const int incl = sh[threadIdx.x];
        const int c = carry_s;
        if (i < NBSCAN) bsum[i] = c + incl - v;   // exclusive
        __syncthreads();
        if (threadIdx.x == 255) carry_s = c + incl;
        __syncthreads();
    }
    if (threadIdx.x == 0) offs[KEYS] = carry_s;
}

__global__ __launch_bounds__(256)
void scan_local(const int* __restrict__ counts, const int* __restrict__ bsum,
                int* __restrict__ offs, int* __restrict__ woff)
{
    __shared__ int sh[256];
    const int i = blockIdx.x * 256 + threadIdx.x;
    const int v = counts[i];
    sh[threadIdx.x] = v;
    __syncthreads();
    for (int st = 1; st < 256; st <<= 1) {
        int t = (threadIdx.x >= st) ? sh[threadIdx.x - st] : 0;
        __syncthreads();
        sh[threadIdx.x] += t;
        __syncthreads();
    }
    const int excl = bsum[blockIdx.x] + sh[threadIdx.x] - v;
    offs[i] = excl;
    woff[i] = excl;
}

__global__ __launch_bounds__(256)
void scatter_edges(const int* __restrict__ pA, const int* __restrict__ pB,
                   const int* __restrict__ flag, int* __restrict__ woff,
                   int* __restrict__ srcs)
{
    const int id = blockIdx.x * 256 + threadIdx.x;
    if (id >= 8 * E_NUM) return;
    int s;
    int key = edge_key(pA, pB, *flag, id, &s);
    int pos = atomicAdd(woff + key, 1);
    srcs[pos] = s;
}

// ---------------- vul aggregation: wave per dst, 16 lanes per edge ----------------
__global__ __launch_bounds__(256)
void vul_gather(const int* __restrict__ srcs, const int* __restrict__ offs,
                const unsigned short* __restrict__ othTab,   // 4 hrS tables, ld 128
                const float* __restrict__ rinHrS,            // 4*N_OTH (recip norms)
                const float* __restrict__ rinHtVul,          // N_VUL
                float* __restrict__ out)                     // ht in cols 0..127; write 128..255
{
    const int d = blockIdx.x * 4 + (threadIdx.x >> 6);
    const int lane = threadIdx.x & 63;
    const int g = lane >> 4, l = lane & 15;

    // b row (f32 ht), channels l*8 .. l*8+7 (same in all 4 groups)
    const float* hrow = out + (size_t)d * 256 + l * 8;
    float b0[8];
    {
        float4 t0 = *(const float4*)(hrow);
        float4 t1 = *(const float4*)(hrow + 4);
        b0[0] = t0.x; b0[1] = t0.y; b0[2] = t0.z; b0[3] = t0.w;
        b0[4] = t1.x; b0[5] = t1.y; b0[6] = t1.z; b0[7] = t1.w;
    }
    const float rnb = rinHtVul[d];

    float acc[4][8];
    float ss[4];
    #pragma unroll
    for (int et = 0; et < 4; ++et) {
        ss[et] = 0.f;
        #pragma unroll
        for (int j = 0; j < 8; ++j) acc[et][j] = 0.f;
    }

    #pragma unroll
    for (int et = 0; et < 4; ++et) {
        const unsigned short* T = othTab + (size_t)et * NO128;
        const float* rA = rinHrS + (size_t)et * N_OTH;
        const int k0 = offs[d * 4 + et], k1 = offs[d * 4 + et + 1];
        for (int p0 = k0; p0 < k1; p0 += 4) {
            const int p = p0 + g;
            const bool ok = (p < k1);
            const int s = srcs[ok ? p : k0];
            bf16x8 av = *(const bf16x8*)(T + (size_t)s * 128 + l * 8);
            float a[8];
            #pragma unroll
            for (int j = 0; j < 8; ++j) a[j] = b2f((unsigned short)av[j]);
            float dp = 0.f;
            #pragma unroll
            for (int j = 0; j < 8; ++j) dp = fmaf(a[j], b0[j], dp);
            dp += __shfl_xor(dp, 1); dp += __shfl_xor(dp, 2);
            dp += __shfl_xor(dp, 4); dp += __shfl_xor(dp, 8);
            const float v = ok ? dp * rA[s] * rnb : 0.f;
            ss[et] += v;
            #pragma unroll
            for (int j = 0; j < 8; ++j) acc[et][j] = fmaf(v, a[j], acc[et][j]);
        }
    }

    // merge group score-sums (each group's ss identical across its 16 lanes)
    #pragma unroll
    for (int et = 0; et < 4; ++et) {
        float t = ss[et];
        t += __shfl_xor(t, 16); t += __shfl_xor(t, 32);
        ss[et] = t;
    }
    const int o0 = offs[d * 4], o1 = offs[d * 4 + 1], o2 = offs[d * 4 + 2],
              o3 = offs[d * 4 + 3], o4 = offs[d * 4 + 4];
    const float m0 = ss[0] / fmaxf((float)(o1 - o0), 1.f);
    const float m1 = ss[1] / fmaxf((float)(o2 - o1), 1.f);
    const float m2 = ss[2] / fmaxf((float)(o3 - o2), 1.f);
    const float m3 = ss[3] / fmaxf((float)(o4 - o3), 1.f);
    const float e0 = expf(m0), e1 = expf(m1), e2 = expf(m2), e3 = expf(m3);
    const float wp = 0.6f / (e0 + e1), wn = 0.4f / (e2 + e3);
    const float w0 = e0 * wp, w1 = e1 * wp, w2 = e2 * wn, w3 = e3 * wn;

    float res[8];
    #pragma unroll
    for (int j = 0; j < 8; ++j) {
        float t = w0 * acc[0][j] + w1 * acc[1][j] + w2 * acc[2][j] + w3 * acc[3][j];
        t += __shfl_xor(t, 16); t += __shfl_xor(t, 32);
        res[j] = t;
    }
    if (g == 0) {
        float4 r0 = {res[0], res[1], res[2], res[3]};
        float4 r1 = {res[4], res[5], res[6], res[7]};
        float* o = out + (size_t)d * 256 + 128 + l * 8;
        *(float4*)(o) = r0;
        *(float4*)(o + 4) = r1;
    }
}

// ---------------- other-ntype aggregation: wave j per dst, 16 lanes per edge ----------------
__global__ __launch_bounds__(256)
void oth_gather(const int* __restrict__ srcs, const int* __restrict__ offs,
                const unsigned short* __restrict__ vulTab,   // 4 hrB tables, ld 128
                const float* __restrict__ rinHrB,            // 4*N_VUL
                const float* __restrict__ rinHtOth,          // 4*N_OTH (j*N_OTH+d)
                float* __restrict__ outO)                    // out + OUT0
{
    const int j = threadIdx.x >> 6;
    const int d = blockIdx.x;
    const int lane = threadIdx.x & 63;
    const int g = lane >> 4, l = lane & 15;

    const float* hrow = outO + ((size_t)j * N_OTH + d) * 256 + l * 8;
    float b0[8];
    {
        float4 t0 = *(const float4*)(hrow);
        float4 t1 = *(const float4*)(hrow + 4);
        b0[0] = t0.x; b0[1] = t0.y; b0[2] = t0.z; b0[3] = t0.w;
        b0[4] = t1.x; b0[5] = t1.y; b0[6] = t1.z; b0[7] = t1.w;
    }
    const float rnb = rinHtOth[j * N_OTH + d];
    const unsigned short* A = vulTab + (size_t)j * NV128;
    const unsigned short* M = vulTab + (size_t)3 * NV128;    // hr_final[0] = We[7] proj
    const float* rA = rinHrB + (size_t)j * N_VUL;

    const int key = VKEYS + j * N_OTH + d;
    const int k0 = offs[key], k1 = offs[key + 1];

    float acc[8];
    #pragma unroll
    for (int jj = 0; jj < 8; ++jj) acc[jj] = 0.f;

    for (int p0 = k0; p0 < k1; p0 += 4) {
        const int p = p0 + g;
        const bool ok = (p < k1);
        const int s = srcs[ok ? p : k0];
        bf16x8 av = *(const bf16x8*)(A + (size_t)s * 128 + l * 8);
        float a[8];
        #pragma unroll
        for (int jj = 0; jj < 8; ++jj) a[jj] = b2f((unsigned short)av[jj]);
        float dp = 0.f;
        #pragma unroll
        for (int jj = 0; jj < 8; ++jj) dp = fmaf(a[jj], b0[jj], dp);
        dp += __shfl_xor(dp, 1); dp += __shfl_xor(dp, 2);
        dp += __shfl_xor(dp, 4); dp += __shfl_xor(dp, 8);
        const float v = ok ? dp * rA[s] * rnb : 0.f;
        if (j == 3) {
            #pragma unroll
            for (int jj = 0; jj < 8; ++jj) acc[jj] = fmaf(v, a[jj], acc[jj]);
        } else {
            bf16x8 mv = *(const bf16x8*)(M + (size_t)s * 128 + l * 8);
            #pragma unroll
            for (int jj = 0; jj < 8; ++jj) acc[jj] = fmaf(v, b2f((unsigned short)mv[jj]), acc[jj]);
        }
    }

    #pragma unroll
    for (int jj = 0; jj < 8; ++jj) {
        float t = acc[jj];
        t += __shfl_xor(t, 16); t += __shfl_xor(t, 32);
        acc[jj] = t;
    }
    if (g == 0) {
        float4 r0 = {acc[0], acc[1], acc[2], acc[3]};
        float4 r1 = {acc[4], acc[5], acc[6], acc[7]};
        float* o = outO + ((size_t)j * N_OTH + d) * 256 + 128 + l * 8;
        *(float4*)(o) = r0;
        *(float4*)(o + 4) = r1;
    }
}

extern "C" void kernel_launch(void* const* d_in, const int* in_sizes, int n_in,
                              void* d_out, int out_size, void* d_ws, size_t ws_size,
                              hipStream_t stream)
{
    // ---- size-based input resolution (proven) ----
    int i_fv = 0, i_fo = 1, i_We = 2, i_Wn = 3, i_bn = 4, i_iA = 5, i_iB = 6;
    {
        int a = -1, b = -1;
        for (int i = 0; i < n_in; ++i) {
            switch (in_sizes[i]) {
                case 25600000: i_fv = i; break;
                case 20480000: i_fo = i; break;
                case   262144: i_We = i; break;
                case   163840: i_Wn = i; break;
                case      640: i_bn = i; break;
                case  3200000: if (a < 0) a = i; else b = i; break;
                default: break;
            }
        }
        if (a >= 0 && b >= 0) { i_iA = a; i_iB = b; }
    }
    const float* feat_vul = (const float*)d_in[i_fv];
    const float* feat_oth = (const float*)d_in[i_fo];
    const float* We = (const float*)d_in[i_We];
    const float* Wn = (const float*)d_in[i_Wn];
    const float* bn = (const float*)d_in[i_bn];
    const int* idxA = (const int*)d_in[i_iA];
    const int* idxB = (const int*)d_in[i_iB];
    float* out = (float*)d_out;

    // ---- workspace carve (~145 MB) ----
    int*   flag    = (int*)d_ws;                           // 4 (zeroed)
    int*   counts  = flag + 4;                             // KEYS (zeroed)
    int*   offs    = counts + KEYS;                        // KEYS+1
    int*   woff    = offs + KEYS + 1;                      // KEYS
    int*   bsum    = woff + KEYS;                          // pad 2048
    int*   srcs    = bsum + 2048;                          // 8*E_NUM
    float* rinHtVul = (float*)(srcs + (size_t)8 * E_NUM);  // N_VUL
    float* rinHtOth = rinHtVul + N_VUL;                    // 4*N_OTH
    float* rinHrB   = rinHtOth + (size_t)4 * N_OTH;        // 4*N_VUL
    float* rinHrS   = rinHrB + (size_t)4 * N_VUL;          // 4*N_OTH
    unsigned short* vulTab = (unsigned short*)(rinHrS + (size_t)4 * N_OTH); // 4*NV128
    unsigned short* othTab = vulTab + 4 * NV128;           // 4*NO128
    unsigned short* Wb     = othTab + 4 * NO128;           // 13*32768

    hipMemsetAsync(d_ws, 0, (4 + (size_t)KEYS) * sizeof(int), stream);

    probe_idx<<<(E_NUM + 255) / 256, 256, 0, stream>>>(idxA, flag);
    pack_w<<<(13 * 32768 + 255) / 256, 256, 0, stream>>>(We, Wn, Wb);

    const size_t OUT0 = (size_t)N_VUL * 256;

    // projections: vul -> ht(f32)+hrB0..3(bf16); oth i -> ht_i(f32)+hrS_i(bf16)
    proj_mfma<<<(N_VUL + 63) / 64, 256, 0, stream>>>(
        feat_vul, Wb, bn, out, vulTab, 5, N_VUL);
    for (int i = 0; i < 4; ++i)
        proj_mfma<<<(N_OTH + 63) / 64, 256, 0, stream>>>(
            feat_oth + (size_t)i * N_OTH * K_DIM,
            Wb + (size_t)(5 + 2 * i) * 32768,
            bn + (size_t)(i + 1) * D_OUT,
            out + OUT0 + (size_t)i * N_OTH * 256,
            othTab + (size_t)i * NO128, 2, N_OTH);

    // reciprocal norms
    rownorm_f<<<(N_VUL + 3) / 4, 256, 0, stream>>>(out, rinHtVul, N_VUL);
    rownorm_f<<<(4 * N_OTH + 3) / 4, 256, 0, stream>>>(out + OUT0, rinHtOth, 4 * N_OTH);
    rownorm_b<<<(4 * N_VUL + 3) / 4, 256, 0, stream>>>(vulTab, rinHrB, 4 * N_VUL);
    rownorm_b<<<(4 * N_OTH + 3) / 4, 256, 0, stream>>>(othTab, rinHrS, 4 * N_OTH);

    // CSR build over all 8 etypes
    hist_edges<<<(8 * E_NUM + 255) / 256, 256, 0, stream>>>(idxA, idxB, flag, counts);
    scan_bsum<<<NBSCAN, 256, 0, stream>>>(counts, bsum);
    scan_top<<<1, 256, 0, stream>>>(bsum, offs);
    scan_local<<<NBSCAN, 256, 0, stream>>>(counts, bsum, offs, woff);
    scatter_edges<<<(8 * E_NUM + 255) / 256, 256, 0, stream>>>(idxA, idxB, flag, woff, srcs);

    // gather-mode aggregation straight into d_out
    vul_gather<<<N_VUL / 4, 256, 0, stream>>>(srcs, offs, othTab, rinHrS, rinHtVul, out);
    oth_gather<<<N_OTH, 256, 0, stream>>>(srcs, offs, vulTab, rinHrB, rinHtOth, out + OUT0);
}